// Round 3
// baseline (789.754 us; speedup 1.0000x reference)
//
#include <hip/hip_runtime.h>
#include <hip/hip_bf16.h>
#include <float.h>

#define NR    32768
#define DDIM  512
#define KC    8192
#define NTILE 64      // KC / 128 code-tiles

typedef __attribute__((ext_vector_type(8))) short short8;   // 8 bf16 = 4 VGPR
typedef __attribute__((ext_vector_type(4))) float f32x4;
typedef const __attribute__((address_space(1))) char gchar_t;
typedef __attribute__((address_space(3))) char lchar_t;

// pack two fp32 -> two bf16 (RNE) in one u32 (low word = first element)
__device__ inline unsigned cvt2(float a, float b) {
    __hip_bfloat162 h = __float22bfloat162_rn(float2{a, b});
    union { __hip_bfloat162 h; unsigned u; } v; v.h = h;
    return v.u;
}

// fp32 latents -> bf16 xb in GEMM-staging order for 256-row blocks:
// granule (RB, it, o, r) at byte offset RB*262144 + it*16384 + o*4096 + r*16,
// RB = 256-row block, it = 32-col K-window, o = octet, r = row in [0,256).
// gemm X staging stays a verbatim linear 16 KB copy; A ds_reads stay 256 B
// contiguous per 16-lane group (zero bank conflicts). Same cvt2 values as
// rounds 1-10 -> operands bit-identical.
__global__ __launch_bounds__(256) void cvt_bf16_kernel(const float* __restrict__ src,
                                                       unsigned* __restrict__ dst) {
    const int RB = blockIdx.x >> 4;      // 128 row-blocks
    const int it = blockIdx.x & 15;      // 16 K-windows
    const int r  = threadIdx.x;          // row within block [0,256)
    const float* p = src + (size_t)(RB * 256 + r) * DDIM + it * 32;
    float4 f[8];
#pragma unroll
    for (int q = 0; q < 8; ++q) f[q] = *(const float4*)(p + q * 4);
    unsigned* out = dst + (size_t)RB * 65536 + it * 4096 + r * 4;   // u32 units
#pragma unroll
    for (int o = 0; o < 4; ++o) {
        uint4 v;
        v.x = cvt2(f[2 * o].x, f[2 * o].y);     v.y = cvt2(f[2 * o].z, f[2 * o].w);
        v.z = cvt2(f[2 * o + 1].x, f[2 * o + 1].y); v.w = cvt2(f[2 * o + 1].z, f[2 * o + 1].w);
        *(uint4*)(out + o * 1024) = v;           // lanes -> contiguous 1 KB per octet
    }
}

// fp32 codebook -> bf16 in fragment-major (octet-transposed) order:
// granule (g, k) of row k stored at ebT[(g*KC + k)*16B]. Coalesced writes;
// scattered reads absorbed by L2/L3 (one-time 8 MB transform).
__global__ __launch_bounds__(256) void cvt_ebT_kernel(const float* __restrict__ src,
                                                      unsigned* __restrict__ dst) {
    const int o = blockIdx.x * 256 + threadIdx.x;   // output granule index
    const int k = o & (KC - 1);
    const int g = o >> 13;                          // KC = 8192
    const float* p = src + (size_t)k * DDIM + g * 8;
    const float4 a = *(const float4*)p;
    const float4 b = *(const float4*)(p + 4);
    uint4 v;
    v.x = cvt2(a.x, a.y); v.y = cvt2(a.z, a.w);
    v.z = cvt2(b.x, b.y); v.w = cvt2(b.z, b.w);
    *(uint4*)(dst + (size_t)o * 4) = v;
}

// sum of squares, one row per 64-thread wave. Per-row arithmetic is
// BITWISE-IDENTICAL to rounds 1-10 -- DO NOT touch.
__global__ __launch_bounds__(256) void rownorm_kernel(const float* __restrict__ src,
                                                      float* __restrict__ dst) {
    const int row  = blockIdx.x * 4 + (threadIdx.x >> 6);
    const int lane = threadIdx.x & 63;
    const float* p = src + (size_t)row * DDIM;
    float s = 0.0f;
#pragma unroll
    for (int i = 0; i < DDIM / 64; ++i) {
        float v = p[lane + i * 64];
        s = __builtin_fmaf(v, v, s);
    }
#pragma unroll
    for (int off = 32; off > 0; off >>= 1) s += __shfl_down(s, off, 64);
    if (lane == 0) dst[row] = s;
}

__global__ __launch_bounds__(256) void semax_kernel(const float* __restrict__ sume,
                                                    float* __restrict__ semax) {
    __shared__ float red[256];
    float m = 0.f;
    for (int i = threadIdx.x; i < KC; i += 256) m = fmaxf(m, sume[i]);
    red[threadIdx.x] = m;
    __syncthreads();
    for (int s = 128; s > 0; s >>= 1) {
        if (threadIdx.x < s) red[threadIdx.x] = fmaxf(red[threadIdx.x], red[threadIdx.x + s]);
        __syncthreads();
    }
    if (threadIdx.x == 0) semax[0] = sqrtf(red[0]);
}

// bf16 MFMA approx-score GEMM + per-(row, code-tile) (min, argmin, 2ndmin).
// Round-11: 256x256 tile, 8 waves (512 thr), BK=32, 16 K-steps.
//  * same counted-vmcnt depth-2 pipeline as round 10 (per-iter VMEM group is
//    still exactly 2 X-DMA + 4 B = 6 -> s_waitcnt vmcnt(6), never 0 in-loop).
//  * B in registers from fragment-major ebT (3-set rotation); X in LDS via
//    linear global_load_lds from 256-row octet-major xb (3-buf rotation).
//  * XCD-chunked block remap: xcd = bid&7 works one 256-col B slab (256 KB,
//    L2-hot) across all 128 row-blocks consecutively. Cache traffic 6->3 GB.
//  * per-(row,col) MFMA accumulation chain bit-identical to round 10.
__global__ __launch_bounds__(512, 2) void gemm_filter_kernel(
        const unsigned* __restrict__ xb, const unsigned* __restrict__ ebT,
        const float* __restrict__ sume,
        float* __restrict__ lmin, float* __restrict__ l2nd, int* __restrict__ lidx) {
    __shared__ alignas(16) char smem[49152];   // X 3 x 16 KB; epilogue overlay 2 x 24 KB

    const int tid = threadIdx.x;
    // XCD-chunked mapping: consecutive per-XCD work shares the B slab.
    const int bid = blockIdx.x;
    const int g   = (bid & 7) * 512 + (bid >> 3);
    const int nbi = g >> 7;                    // [0,32): 256-col slab
    const int mb  = g & 127;                   // [0,128): 256-row block
    const int row0 = mb * 256, col0 = nbi * 256;
    const int lane = tid & 63, w = tid >> 6;   // 8 waves
    const int wy = w >> 2, wx = w & 3;         // 2M x 4N wave grid
    const int l15 = lane & 15, q4 = lane >> 4; // q4 in [0,4)

    f32x4 acc[8][4];
#pragma unroll
    for (int i = 0; i < 8; ++i)
#pragma unroll
        for (int j = 0; j < 4; ++j) acc[i][j] = f32x4{0.f, 0.f, 0.f, 0.f};

    // X staging: region R = w*2+t (16 regions x 1 KB = 16 KB tile), verbatim
    // linear copy of the (mb, it) tile; source==dest layout.
    const char* xg[2];
#pragma unroll
    for (int t = 0; t < 2; ++t)
        xg[t] = (const char*)xb + (size_t)mb * 262144 + ((w * 2 + t) << 10) + (lane << 4);
    // A-fragment byte offset: octet q4, row wy*128 + 16i + l15
    const int aoff = (q4 << 12) + ((wy * 128 + l15) << 4);   // + i*256

    // B global base: granule (g = q4 + 4it, col = col0 + 64wx + 16j + l15)
    const unsigned* bptr = ebT + ((size_t)(q4 * KC + col0 + wx * 64 + l15)) * 4;
    // j-stride: 16 cols = 64 u32; it-stride: 4*KC granules = 131072 u32

    short8 B[3][4];

    // prologue: stage tiles 0,1 (X -> LDS bufs 0,1; B -> reg sets 0,1)
#pragma unroll
    for (int p = 0; p < 2; ++p) {
#pragma unroll
        for (int t = 0; t < 2; ++t)
            __builtin_amdgcn_global_load_lds((gchar_t*)(xg[t] + p * 16384),
                (lchar_t*)(smem + p * 16384 + ((w * 2 + t) << 10) + (lane << 4)), 16, 0, 0);
        const unsigned* bn = bptr + (size_t)p * 131072;
#pragma unroll
        for (int j = 0; j < 4; ++j) B[p][j] = *(const short8*)(bn + j * 64);
    }

#pragma unroll
    for (int it = 0; it < 16; ++it) {
        // Drain tile it's issue-group (6 VMEM), keep tile it+1's in flight.
        if (it < 15) asm volatile("s_waitcnt vmcnt(6)" ::: "memory");
        else         asm volatile("s_waitcnt vmcnt(0)" ::: "memory");
        __builtin_amdgcn_sched_barrier(0);
        __builtin_amdgcn_s_barrier();
        __builtin_amdgcn_sched_barrier(0);
        // issue tile it+2: X into buf (it+2)%3 (released by the barrier above)
        if (it + 2 < 16) {
#pragma unroll
            for (int t = 0; t < 2; ++t)
                __builtin_amdgcn_global_load_lds((gchar_t*)(xg[t] + (it + 2) * 16384),
                    (lchar_t*)(smem + ((it + 2) % 3) * 16384 + ((w * 2 + t) << 10) + (lane << 4)), 16, 0, 0);
            const unsigned* bn = bptr + (size_t)(it + 2) * 131072;
#pragma unroll
            for (int j = 0; j < 4; ++j) B[(it + 2) % 3][j] = *(const short8*)(bn + j * 64);
        }
        __builtin_amdgcn_sched_barrier(0);
        // compute tile it
        const char* Xc = smem + (it % 3) * 16384;
        short8 A[8];
#pragma unroll
        for (int i = 0; i < 8; ++i)
            A[i] = *(const short8*)(Xc + aoff + i * 256);
#pragma unroll
        for (int i = 0; i < 8; ++i)
#pragma unroll
            for (int j = 0; j < 4; ++j)
                acc[i][j] = __builtin_amdgcn_mfma_f32_16x16x32_bf16(A[i], B[it % 3][j], acc[i][j], 0, 0, 0);
    }

    // ---- epilogue: per-row (min, argmin, 2ndmin) over TWO 128-code tiles.
    float se[4];
#pragma unroll
    for (int j = 0; j < 4; ++j) se[j] = sume[col0 + wx * 64 + 16 * j + l15];

    __syncthreads();   // all waves done reading LDS before scratch overlays it
    const int tile = wx >> 1;   // which 128-code tile this wave contributes to
    float* pv1 = (float*)(smem + tile * 24576);            // [256][8]
    float* pv2 = (float*)(smem + tile * 24576 + 8192);     // [256][8]
    int*   pk1 = (int*)  (smem + tile * 24576 + 16384);    // [256][8]

#pragma unroll
    for (int i = 0; i < 8; ++i) {
#pragma unroll
        for (int reg = 0; reg < 4; ++reg) {
            float v1 = FLT_MAX, v2 = FLT_MAX; int k1 = 0;
#pragma unroll
            for (int j = 0; j < 4; ++j) {
                const float s = __builtin_fmaf(-2.f, acc[i][j][reg], se[j]);
                const int c = col0 + wx * 64 + 16 * j + l15;
                if (s < v1) { v2 = v1; v1 = s; k1 = c; }
                else        { v2 = fminf(v2, s); }
            }
            // merge groups of 4 l15-lanes (exact ties leave l2nd==lmin -> the
            // rescore full-scans the tile, so tie-side argmin choice is moot)
#pragma unroll
            for (int m = 1; m <= 2; m <<= 1) {
                const float ov1 = __shfl_xor(v1, m, 64);
                const int   ok1 = __shfl_xor(k1, m, 64);
                const float ov2 = __shfl_xor(v2, m, 64);
                const float nv2 = fminf(fmaxf(v1, ov1), fminf(v2, ov2));
                if (ov1 < v1) { v1 = ov1; k1 = ok1; }
                v2 = nv2;
            }
            if ((l15 & 3) == 0) {
                const int rowl = wy * 128 + 16 * i + 4 * q4 + reg;   // [0,256)
                const int c8   = (wx & 1) * 4 + (l15 >> 2);
                const int slot = rowl * 8 + ((c8 + rowl) & 7);   // rotation swizzle
                pv1[slot] = v1; pv2[slot] = v2; pk1[slot] = k1;
            }
        }
    }
    __syncthreads();
    {
        const int tl  = tid >> 8;       // tile 0/1
        const int row = tid & 255;
        const float* qv1 = (const float*)(smem + tl * 24576);
        const float* qv2 = (const float*)(smem + tl * 24576 + 8192);
        const int*   qk1 = (const int*)  (smem + tl * 24576 + 16384);
        float g1 = FLT_MAX, g2 = FLT_MAX; int gk = 0;
#pragma unroll
        for (int c = 0; c < 8; ++c) {
            const int slot = row * 8 + ((c + row) & 7);
            const float p1 = qv1[slot];
            const float p2 = qv2[slot];
            const int   pk = qk1[slot];
            if (p1 < g1) { g2 = fminf(g1, p2); g1 = p1; gk = pk; }
            else         { g2 = fminf(g2, p1); }
        }
        // transposed stat layout [nb][row]: 1 KB contiguous per array per tile
        const size_t o = (size_t)(nbi * 2 + tl) * NR + row0 + row;
        lmin[o] = g1; l2nd[o] = g2; lidx[o] = gk;
    }
}

// exact rescore of provably-covering candidate set; one wave per row.
// margin = 2*(2^-7*||x||*||e||max + 6.5e-5): bf16-RNE dot error bound + two
// half-ulp(512) roundings in the exact formula, doubled for two-sidedness.
__global__ __launch_bounds__(256) void rescore_kernel(
        const float* __restrict__ x, const float* __restrict__ e,
        const float* __restrict__ sumx, const float* __restrict__ sume,
        const float* __restrict__ semax,
        const float* __restrict__ lmin, const float* __restrict__ l2nd,
        const int* __restrict__ lidx, int* __restrict__ inds) {
    __shared__ float xr[4][DDIM];
    __shared__ int list[4][64];

    const int w = threadIdx.x >> 6, lane = threadIdx.x & 63;
    const int row = blockIdx.x * 4 + w;

    // transposed stat layout [tile][row] (written coalesced by the gemm)
    const float lm = lmin[(size_t)lane * NR + row];
    const float l2 = l2nd[(size_t)lane * NR + row];
    const int   li = lidx[(size_t)lane * NR + row];

    float mr = lm;
#pragma unroll
    for (int m = 1; m < 64; m <<= 1) mr = fminf(mr, __shfl_xor(mr, m, 64));

    const float sx  = sumx[row];
    const float thr = mr + (0.0157f * sqrtf(sx) * semax[0] + 1.4e-4f);

    const bool single = (lm <= thr) && (l2 > thr);
    const unsigned long long bs = __ballot(single);
    const int pos = __popcll(bs & ((1ull << lane) - 1ull));
    if (single) list[w][pos] = li;
    const int nS = __popcll(bs);
    unsigned long long bf = __ballot(l2 <= thr);

    {
        const float* px = x + (size_t)row * DDIM + lane * 8;
        *(float4*)(&xr[w][lane * 8])     = *(const float4*)(px);
        *(float4*)(&xr[w][lane * 8 + 4]) = *(const float4*)(px + 4);
    }
    __syncthreads();

    float bd = FLT_MAX; int bk = 0x7fffffff;
    // exact dist: float4 loads, FMA order identical to rounds 1-10
#define EVAL(KK)                                                             \
    {                                                                        \
        const int k_ = (KK);                                                 \
        const float4* ep4 = (const float4*)(e + ((size_t)k_ << 9));          \
        float dot = 0.f;                                                     \
        _Pragma("unroll 4")                                                  \
        for (int d4 = 0; d4 < 128; ++d4) {                                   \
            const float4 ev = ep4[d4];                                       \
            const float4 xv = *(const float4*)(&xr[w][d4 * 4]);              \
            dot = __builtin_fmaf(xv.x, ev.x, dot);                           \
            dot = __builtin_fmaf(xv.y, ev.y, dot);                           \
            dot = __builtin_fmaf(xv.z, ev.z, dot);                           \
            dot = __builtin_fmaf(xv.w, ev.w, dot);                           \
        }                                                                    \
        const float t1   = __fadd_rn(sx, sume[k_]);                          \
        const float dist = __fsub_rn(t1, __fadd_rn(dot, dot));               \
        if (dist < bd || (dist == bd && k_ < bk)) { bd = dist; bk = k_; }    \
    }

    if (lane < nS) EVAL(list[w][lane]);
    while (bf) {
        const int t = __ffsll((long long)bf) - 1;
        bf &= bf - 1;
        EVAL(128 * t + lane);
        EVAL(128 * t + 64 + lane);
    }
#undef EVAL

#pragma unroll
    for (int m = 1; m < 64; m <<= 1) {
        const float od = __shfl_xor(bd, m, 64);
        const int   ok = __shfl_xor(bk, m, 64);
        if (od < bd || (od == bd && ok < bk)) { bd = od; bk = ok; }
    }
    if (lane == 0) inds[row] = bk;
}

// out = x + (e[ind] - x), exact elementwise fp32 STE
__global__ __launch_bounds__(256) void writeout_kernel(const float* __restrict__ x,
                                                       const float* __restrict__ e,
                                                       const int* __restrict__ inds,
                                                       float* __restrict__ out) {
    const int t  = blockIdx.x * blockDim.x + threadIdx.x;
    const int n  = t >> 7;
    const int dq = (t & 127) * 4;
    const int ind = inds[n];
    const float4 xv = *(const float4*)(x + (size_t)n * DDIM + dq);
    const float4 ev = *(const float4*)(e + (size_t)ind * DDIM + dq);
    float4 o;
    o.x = __fadd_rn(xv.x, __fsub_rn(ev.x, xv.x));
    o.y = __fadd_rn(xv.y, __fsub_rn(ev.y, xv.y));
    o.z = __fadd_rn(xv.z, __fsub_rn(ev.z, xv.z));
    o.w = __fadd_rn(xv.w, __fsub_rn(ev.w, xv.w));
    *(float4*)(out + (size_t)n * DDIM + dq) = o;
}

extern "C" void kernel_launch(void* const* d_in, const int* in_sizes, int n_in,
                              void* d_out, int out_size, void* d_ws, size_t ws_size,
                              hipStream_t stream) {
    const float* lat = (const float*)d_in[0];   // (16,2048,512) fp32
    const float* emb = (const float*)d_in[1];   // (8192,512) fp32
    float* out = (float*)d_out;

    char* ws = (char*)d_ws;
    size_t off = 0;
    float*    sume  = (float*)(ws + off);    off += (size_t)KC * 4;
    float*    sumx  = (float*)(ws + off);    off += (size_t)NR * 4;
    float*    semax = (float*)(ws + off);    off += 256;
    float*    lmin  = (float*)(ws + off);    off += (size_t)NR * NTILE * 4;
    float*    l2nd  = (float*)(ws + off);    off += (size_t)NR * NTILE * 4;
    int*      lidx  = (int*)  (ws + off);    off += (size_t)NR * NTILE * 4;
    int*      inds  = (int*)  (ws + off);    off += (size_t)NR * 4;
    unsigned* xb    = (unsigned*)(ws + off); off += (size_t)NR * DDIM * 2;
    unsigned* ebT   = (unsigned*)(ws + off); off += (size_t)KC * DDIM * 2;

    cvt_bf16_kernel<<<2048, 256, 0, stream>>>(lat, xb);            // 128 RB x 16 it
    cvt_ebT_kernel<<<(KC * DDIM / 8) / 256, 256, 0, stream>>>(emb, ebT);
    rownorm_kernel<<<KC / 4, 256, 0, stream>>>(emb, sume);
    rownorm_kernel<<<NR / 4, 256, 0, stream>>>(lat, sumx);
    semax_kernel<<<1, 256, 0, stream>>>(sume, semax);
    gemm_filter_kernel<<<4096, 512, 0, stream>>>(xb, ebT, sume, lmin, l2nd, lidx);
    rescore_kernel<<<NR / 4, 256, 0, stream>>>(lat, emb, sumx, sume, semax, lmin, l2nd, lidx, inds);
    writeout_kernel<<<(NR * DDIM / 4) / 256, 256, 0, stream>>>(lat, emb, inds, out);
}

// Round 4
// 732.065 us; speedup vs baseline: 1.0788x; 1.0788x over previous
//
#include <hip/hip_runtime.h>
#include <hip/hip_bf16.h>
#include <float.h>

#define NR    32768
#define DDIM  512
#define KC    8192
#define NTILE 64      // KC / 128 code-tiles

typedef __attribute__((ext_vector_type(8))) short short8;   // 8 bf16 = 4 VGPR
typedef __attribute__((ext_vector_type(4))) float f32x4;
typedef const __attribute__((address_space(1))) char gchar_t;
typedef __attribute__((address_space(3))) char lchar_t;

// pack two fp32 -> two bf16 (RNE) in one u32 (low word = first element)
__device__ inline unsigned cvt2(float a, float b) {
    __hip_bfloat162 h = __float22bfloat162_rn(float2{a, b});
    union { __hip_bfloat162 h; unsigned u; } v; v.h = h;
    return v.u;
}

// fp32 latents -> bf16 xb in GEMM-staging order: granule (RB, it, o, r) at
// byte offset RB*131072 + it*8192 + o*2048 + r*16, where RB = 128-row block,
// it = 32-col K-window, o = octet (8 bf16) within the window, r = row.
// Makes the gemm's X staging a verbatim linear 8 KB copy (global_load_lds
// needs a linear dest) AND makes the A-fragment ds_reads 256 B-contiguous
// per 16-lane group -> near-zero LDS bank conflicts, no swizzle.
// Values bit-identical to the original row-major xb (same cvt2).
__global__ __launch_bounds__(256) void cvt_bf16_kernel(const float* __restrict__ src,
                                                       unsigned* __restrict__ dst) {
    const int RB = blockIdx.x >> 4;      // 256 row-blocks
    const int it = blockIdx.x & 15;      // 16 K-windows
    const int r  = threadIdx.x & 127;    // row within block
    const int h  = threadIdx.x >> 7;     // octet pair (o = 2h, 2h+1)
    const float* p = src + (size_t)(RB * 128 + r) * DDIM + it * 32 + h * 16;
    const float4 a = *(const float4*)p;          // full 64 B line per lane
    const float4 b = *(const float4*)(p + 4);
    const float4 c = *(const float4*)(p + 8);
    const float4 d = *(const float4*)(p + 12);
    unsigned* out = dst + (size_t)RB * 32768 + it * 2048 + h * 1024 + r * 4;
    uint4 g0, g1;
    g0.x = cvt2(a.x, a.y); g0.y = cvt2(a.z, a.w);
    g0.z = cvt2(b.x, b.y); g0.w = cvt2(b.z, b.w);
    g1.x = cvt2(c.x, c.y); g1.y = cvt2(c.z, c.w);
    g1.z = cvt2(d.x, d.y); g1.w = cvt2(d.z, d.w);
    *(uint4*)out         = g0;           // octet 2h   : lanes -> contiguous 1 KB
    *(uint4*)(out + 512) = g1;           // octet 2h+1 : +2048 B
}

// fp32 codebook -> bf16 in fragment-major (octet-transposed) order:
// granule (g, k) of row k stored at ebT[(g*KC + k)*16B]. Coalesced writes;
// scattered reads absorbed by L2/L3 (one-time 8 MB transform).
__global__ __launch_bounds__(256) void cvt_ebT_kernel(const float* __restrict__ src,
                                                      unsigned* __restrict__ dst) {
    const int o = blockIdx.x * 256 + threadIdx.x;   // output granule index
    const int k = o & (KC - 1);
    const int g = o >> 13;                          // KC = 8192
    const float* p = src + (size_t)k * DDIM + g * 8;
    const float4 a = *(const float4*)p;
    const float4 b = *(const float4*)(p + 4);
    uint4 v;
    v.x = cvt2(a.x, a.y); v.y = cvt2(a.z, a.w);
    v.z = cvt2(b.x, b.y); v.w = cvt2(b.z, b.w);
    *(uint4*)(dst + (size_t)o * 4) = v;
}

// sum of squares, one row per 64-thread wave. Per-row arithmetic is
// BITWISE-IDENTICAL to all prior rounds -- DO NOT touch.
__global__ __launch_bounds__(256) void rownorm_kernel(const float* __restrict__ src,
                                                      float* __restrict__ dst) {
    const int row  = blockIdx.x * 4 + (threadIdx.x >> 6);
    const int lane = threadIdx.x & 63;
    const float* p = src + (size_t)row * DDIM;
    float s = 0.0f;
#pragma unroll
    for (int i = 0; i < DDIM / 64; ++i) {
        float v = p[lane + i * 64];
        s = __builtin_fmaf(v, v, s);
    }
#pragma unroll
    for (int off = 32; off > 0; off >>= 1) s += __shfl_down(s, off, 64);
    if (lane == 0) dst[row] = s;
}

__global__ __launch_bounds__(256) void semax_kernel(const float* __restrict__ sume,
                                                    float* __restrict__ semax) {
    __shared__ float red[256];
    float m = 0.f;
    for (int i = threadIdx.x; i < KC; i += 256) m = fmaxf(m, sume[i]);
    red[threadIdx.x] = m;
    __syncthreads();
    for (int s = 128; s > 0; s >>= 1) {
        if (threadIdx.x < s) red[threadIdx.x] = fmaxf(red[threadIdx.x], red[threadIdx.x + s]);
        __syncthreads();
    }
    if (threadIdx.x == 0) semax[0] = sqrtf(red[0]);
}

// bf16 MFMA approx-score GEMM + per-(row, code-tile) (min, argmin, 2ndmin).
// Round-12 = the verified round-2/round-10 structure (332 us measured):
//  * counted-vmcnt pipeline: raw s_barrier + s_waitcnt vmcnt(6) per iter
//    (never 0 in the loop); X rotates 3 LDS buffers, B rotates 3 reg sets.
//  * octet-major xb: X staging = verbatim linear 8 KB copy; A ds_reads are
//    256 B contiguous per 16-lane group -> SQ_LDS_BANK_CONFLICT ~ 3e6
//    (epilogue only).
//  * implicit nb%8 -> XCD pinning (bid = mb*64+nb, xcd = bid%8): each XCD's
//    B working set is 1 MB (L2-resident forever); X panels fetched once per
//    XCD. FETCH ~ 135 MB. DO NOT remap blocks (round-3 regression: 541 MB).
//  * stats stored [row][tile] (round-0 layout): strided 4 B writes cost
//    ~196 MB WRITE_SIZE but are OFF the critical path (write queue absorbs;
//    gemm is not BW-bound); the [nb][row] transpose saved no gemm time and
//    cost rescore ~40 us in sector-fragmented reads (round-2/3 evidence).
__global__ __launch_bounds__(256) void gemm_filter_kernel(
        const unsigned* __restrict__ xb, const unsigned* __restrict__ ebT,
        const float* __restrict__ sume,
        float* __restrict__ lmin, float* __restrict__ l2nd, int* __restrict__ lidx) {
    __shared__ alignas(16) char smem[24576];   // X 3 x 8 KB; epilogue overlay

    const int tid  = threadIdx.x;
    const int nb   = blockIdx.x & (NTILE - 1);
    const int mb   = blockIdx.x >> 6;
    const int row0 = mb * 128, col0 = nb * 128;
    const int lane = tid & 63, w = tid >> 6;
    const int wy = w >> 1, wx = w & 1;
    const int l15 = lane & 15, q4 = lane >> 4;   // q4 in [0,4)

    f32x4 acc[4][4];
#pragma unroll
    for (int i = 0; i < 4; ++i)
#pragma unroll
        for (int j = 0; j < 4; ++j) acc[i][j] = f32x4{0.f, 0.f, 0.f, 0.f};

    // X staging: region R = w*2+t, 1 KB linear per gload_lds, source==dest
    // layout (verbatim copy of the 8 KB (mb, it) tile).
    const char* xg[2];
#pragma unroll
    for (int t = 0; t < 2; ++t)
        xg[t] = (const char*)xb + (size_t)mb * 131072 + ((w * 2 + t) << 10) + (lane << 4);
    // A-fragment byte offset in octet-major tile: o=q4, row=64*wy+16i+l15
    const int aoff = (q4 << 11) + ((64 * wy + l15) << 4);   // + i*256

    // B global base: granule (g = q4, col = col0 + 64wx + l15), u32 units
    const unsigned* bptr = ebT + ((size_t)(q4 * KC + col0 + 64 * wx + l15)) * 4;
    // j-stride: 16 cols = 64 u32; tile-stride: 4*KC granules = 131072 u32

    short8 B[3][4];

    // prologue: stage tiles 0,1 (X -> LDS bufs 0,1; B -> reg sets 0,1)
#pragma unroll
    for (int p = 0; p < 2; ++p) {
#pragma unroll
        for (int t = 0; t < 2; ++t)
            __builtin_amdgcn_global_load_lds((gchar_t*)(xg[t] + p * 8192),
                (lchar_t*)(smem + p * 8192 + ((w * 2 + t) << 10) + (lane << 4)), 16, 0, 0);
        const unsigned* bn = bptr + (size_t)p * 131072;
#pragma unroll
        for (int j = 0; j < 4; ++j) B[p][j] = *(const short8*)(bn + j * 64);
    }

#pragma unroll
    for (int it = 0; it < 16; ++it) {
        // Drain whole issue-group of tile `it` (6 VMEM: 2 X-DMA + 4 B),
        // keep tile it+1's group (6) in flight across the barrier.
        if (it < 15) asm volatile("s_waitcnt vmcnt(6)" ::: "memory");
        else         asm volatile("s_waitcnt vmcnt(0)" ::: "memory");
        __builtin_amdgcn_sched_barrier(0);
        __builtin_amdgcn_s_barrier();
        __builtin_amdgcn_sched_barrier(0);
        // issue tile it+2: X into buf (it+2)%3 (= buf (it-1)%3, released by
        // the barrier above), B into reg set (it+2)%3.
        if (it + 2 < 16) {
#pragma unroll
            for (int t = 0; t < 2; ++t)
                __builtin_amdgcn_global_load_lds((gchar_t*)(xg[t] + (it + 2) * 8192),
                    (lchar_t*)(smem + ((it + 2) % 3) * 8192 + ((w * 2 + t) << 10) + (lane << 4)), 16, 0, 0);
            const unsigned* bn = bptr + (size_t)(it + 2) * 131072;
#pragma unroll
            for (int j = 0; j < 4; ++j) B[(it + 2) % 3][j] = *(const short8*)(bn + j * 64);
        }
        __builtin_amdgcn_sched_barrier(0);
        // compute tile it
        const char* Xc = smem + (it % 3) * 8192;
        short8 A[4];
#pragma unroll
        for (int i = 0; i < 4; ++i)
            A[i] = *(const short8*)(Xc + aoff + i * 256);
#pragma unroll
        for (int i = 0; i < 4; ++i)
#pragma unroll
            for (int j = 0; j < 4; ++j)
                acc[i][j] = __builtin_amdgcn_mfma_f32_16x16x32_bf16(A[i], B[it % 3][j], acc[i][j], 0, 0, 0);
    }

    // ---- epilogue: per-row (min, argmin, 2ndmin) over this 128-code tile.
    float se[4];
#pragma unroll
    for (int j = 0; j < 4; ++j) se[j] = sume[col0 + 64 * wx + 16 * j + l15];

    __syncthreads();   // all waves done reading LDS before scratch overlays it
    float* pv1 = (float*)smem;             // [128][8]
    float* pv2 = (float*)(smem + 4096);    // [128][8]
    int*   pk1 = (int*)(smem + 8192);      // [128][8]

#pragma unroll
    for (int i = 0; i < 4; ++i) {
#pragma unroll
        for (int reg = 0; reg < 4; ++reg) {
            float v1 = FLT_MAX, v2 = FLT_MAX; int k1 = 0;
#pragma unroll
            for (int j = 0; j < 4; ++j) {
                const float s = __builtin_fmaf(-2.f, acc[i][j][reg], se[j]);
                const int c = col0 + 64 * wx + 16 * j + l15;
                if (s < v1) { v2 = v1; v1 = s; k1 = c; }
                else        { v2 = fminf(v2, s); }
            }
            // merge groups of 4 l15-lanes (exact ties leave l2nd==lmin -> the
            // rescore full-scans the tile, so tie-side argmin choice is moot)
#pragma unroll
            for (int m = 1; m <= 2; m <<= 1) {
                const float ov1 = __shfl_xor(v1, m, 64);
                const int   ok1 = __shfl_xor(k1, m, 64);
                const float ov2 = __shfl_xor(v2, m, 64);
                const float nv2 = fminf(fmaxf(v1, ov1), fminf(v2, ov2));
                if (ov1 < v1) { v1 = ov1; k1 = ok1; }
                v2 = nv2;
            }
            if ((l15 & 3) == 0) {
                const int rowl = 64 * wy + 16 * i + 4 * q4 + reg;
                const int c8   = wx * 4 + (l15 >> 2);
                const int slot = rowl * 8 + ((c8 + rowl) & 7);   // rotation swizzle
                pv1[slot] = v1; pv2[slot] = v2; pk1[slot] = k1;
            }
        }
    }
    __syncthreads();
    if (tid < 128) {
        float g1 = FLT_MAX, g2 = FLT_MAX; int gk = 0;
#pragma unroll
        for (int c = 0; c < 8; ++c) {
            const int slot = tid * 8 + ((c + tid) & 7);
            const float p1 = pv1[slot];
            const float p2 = pv2[slot];
            const int   pk = pk1[slot];
            if (p1 < g1) { g2 = fminf(g1, p2); g1 = p1; gk = pk; }
            else         { g2 = fminf(g2, p1); }
        }
        // [row][tile] layout: strided 4 B writes (off critical path); keeps
        // rescore's reads fully coalesced (256 B per wave per array).
        const size_t o = (size_t)(row0 + tid) * NTILE + nb;
        lmin[o] = g1; l2nd[o] = g2; lidx[o] = gk;
    }
}

// exact rescore of provably-covering candidate set; one wave per row.
// margin = 2*(2^-7*||x||*||e||max + 6.5e-5): bf16-RNE dot error bound + two
// half-ulp(512) roundings in the exact formula, doubled for two-sidedness.
__global__ __launch_bounds__(256) void rescore_kernel(
        const float* __restrict__ x, const float* __restrict__ e,
        const float* __restrict__ sumx, const float* __restrict__ sume,
        const float* __restrict__ semax,
        const float* __restrict__ lmin, const float* __restrict__ l2nd,
        const int* __restrict__ lidx, int* __restrict__ inds) {
    __shared__ float xr[4][DDIM];
    __shared__ int list[4][64];

    const int w = threadIdx.x >> 6, lane = threadIdx.x & 63;
    const int row = blockIdx.x * 4 + w;

    // [row][tile] layout: coalesced 256 B per wave per array
    const float lm = lmin[(size_t)row * NTILE + lane];
    const float l2 = l2nd[(size_t)row * NTILE + lane];
    const int   li = lidx[(size_t)row * NTILE + lane];

    float mr = lm;
#pragma unroll
    for (int m = 1; m < 64; m <<= 1) mr = fminf(mr, __shfl_xor(mr, m, 64));

    const float sx  = sumx[row];
    const float thr = mr + (0.0157f * sqrtf(sx) * semax[0] + 1.4e-4f);

    const bool single = (lm <= thr) && (l2 > thr);
    const unsigned long long bs = __ballot(single);
    const int pos = __popcll(bs & ((1ull << lane) - 1ull));
    if (single) list[w][pos] = li;
    const int nS = __popcll(bs);
    unsigned long long bf = __ballot(l2 <= thr);

    {
        const float* px = x + (size_t)row * DDIM + lane * 8;
        *(float4*)(&xr[w][lane * 8])     = *(const float4*)(px);
        *(float4*)(&xr[w][lane * 8 + 4]) = *(const float4*)(px + 4);
    }
    __syncthreads();

    float bd = FLT_MAX; int bk = 0x7fffffff;
    // exact dist: float4 loads, FMA order identical to all prior rounds
#define EVAL(KK)                                                             \
    {                                                                        \
        const int k_ = (KK);                                                 \
        const float4* ep4 = (const float4*)(e + ((size_t)k_ << 9));          \
        float dot = 0.f;                                                     \
        _Pragma("unroll 4")                                                  \
        for (int d4 = 0; d4 < 128; ++d4) {                                   \
            const float4 ev = ep4[d4];                                       \
            const float4 xv = *(const float4*)(&xr[w][d4 * 4]);              \
            dot = __builtin_fmaf(xv.x, ev.x, dot);                           \
            dot = __builtin_fmaf(xv.y, ev.y, dot);                           \
            dot = __builtin_fmaf(xv.z, ev.z, dot);                           \
            dot = __builtin_fmaf(xv.w, ev.w, dot);                           \
        }                                                                    \
        const float t1   = __fadd_rn(sx, sume[k_]);                          \
        const float dist = __fsub_rn(t1, __fadd_rn(dot, dot));               \
        if (dist < bd || (dist == bd && k_ < bk)) { bd = dist; bk = k_; }    \
    }

    if (lane < nS) EVAL(list[w][lane]);
    while (bf) {
        const int t = __ffsll((long long)bf) - 1;
        bf &= bf - 1;
        EVAL(128 * t + lane);
        EVAL(128 * t + 64 + lane);
    }
#undef EVAL

#pragma unroll
    for (int m = 1; m < 64; m <<= 1) {
        const float od = __shfl_xor(bd, m, 64);
        const int   ok = __shfl_xor(bk, m, 64);
        if (od < bd || (od == bd && ok < bk)) { bd = od; bk = ok; }
    }
    if (lane == 0) inds[row] = bk;
}

// out = x + (e[ind] - x), exact elementwise fp32 STE
__global__ __launch_bounds__(256) void writeout_kernel(const float* __restrict__ x,
                                                       const float* __restrict__ e,
                                                       const int* __restrict__ inds,
                                                       float* __restrict__ out) {
    const int t  = blockIdx.x * blockDim.x + threadIdx.x;
    const int n  = t >> 7;
    const int dq = (t & 127) * 4;
    const int ind = inds[n];
    const float4 xv = *(const float4*)(x + (size_t)n * DDIM + dq);
    const float4 ev = *(const float4*)(e + (size_t)ind * DDIM + dq);
    float4 o;
    o.x = __fadd_rn(xv.x, __fsub_rn(ev.x, xv.x));
    o.y = __fadd_rn(xv.y, __fsub_rn(ev.y, xv.y));
    o.z = __fadd_rn(xv.z, __fsub_rn(ev.z, xv.z));
    o.w = __fadd_rn(xv.w, __fsub_rn(ev.w, xv.w));
    *(float4*)(out + (size_t)n * DDIM + dq) = o;
}

extern "C" void kernel_launch(void* const* d_in, const int* in_sizes, int n_in,
                              void* d_out, int out_size, void* d_ws, size_t ws_size,
                              hipStream_t stream) {
    const float* lat = (const float*)d_in[0];   // (16,2048,512) fp32
    const float* emb = (const float*)d_in[1];   // (8192,512) fp32
    float* out = (float*)d_out;

    char* ws = (char*)d_ws;
    size_t off = 0;
    float*    sume  = (float*)(ws + off);    off += (size_t)KC * 4;
    float*    sumx  = (float*)(ws + off);    off += (size_t)NR * 4;
    float*    semax = (float*)(ws + off);    off += 256;
    float*    lmin  = (float*)(ws + off);    off += (size_t)NR * NTILE * 4;
    float*    l2nd  = (float*)(ws + off);    off += (size_t)NR * NTILE * 4;
    int*      lidx  = (int*)  (ws + off);    off += (size_t)NR * NTILE * 4;
    int*      inds  = (int*)  (ws + off);    off += (size_t)NR * 4;
    unsigned* xb    = (unsigned*)(ws + off); off += (size_t)NR * DDIM * 2;
    unsigned* ebT   = (unsigned*)(ws + off); off += (size_t)KC * DDIM * 2;

    cvt_bf16_kernel<<<4096, 256, 0, stream>>>(lat, xb);            // 256 RB x 16 it
    cvt_ebT_kernel<<<(KC * DDIM / 8) / 256, 256, 0, stream>>>(emb, ebT);
    rownorm_kernel<<<KC / 4, 256, 0, stream>>>(emb, sume);
    rownorm_kernel<<<NR / 4, 256, 0, stream>>>(lat, sumx);
    semax_kernel<<<1, 256, 0, stream>>>(sume, semax);
    gemm_filter_kernel<<<(NR / 128) * NTILE, 256, 0, stream>>>(xb, ebT, sume, lmin, l2nd, lidx);
    rescore_kernel<<<NR / 4, 256, 0, stream>>>(lat, emb, sumx, sume, semax, lmin, l2nd, lidx, inds);
    writeout_kernel<<<(NR * DDIM / 4) / 256, 256, 0, stream>>>(lat, emb, inds, out);
}

// Round 5
// 726.300 us; speedup vs baseline: 1.0874x; 1.0079x over previous
//
#include <hip/hip_runtime.h>
#include <hip/hip_bf16.h>
#include <float.h>

#define NR    32768
#define DDIM  512
#define KC    8192
#define NTILE 64      // KC / 128 code-tiles

typedef __attribute__((ext_vector_type(8))) short short8;   // 8 bf16 = 4 VGPR
typedef __attribute__((ext_vector_type(4))) float f32x4;
typedef const __attribute__((address_space(1))) char gchar_t;
typedef __attribute__((address_space(3))) char lchar_t;

// pack two fp32 -> two bf16 (RNE) in one u32 (low word = first element)
__device__ inline unsigned cvt2(float a, float b) {
    __hip_bfloat162 h = __float22bfloat162_rn(float2{a, b});
    union { __hip_bfloat162 h; unsigned u; } v; v.h = h;
    return v.u;
}

// fp32 latents -> bf16 xb in GEMM-staging (octet-major) order: granule
// (RB, og, r) at u32 offset RB*32768 + og*512 + r*4, where RB = 128-row
// block, og = it*4+o in [0,64) (8-float granule-column), r = row in [0,128).
// Round-13 fix: round-2/4's version read 64 B/lane at 2048 B stride (64
// cache-line requests per wave-load -> request-bound, ~+40 us vs round 0).
// Now each WAVE reads one full row contiguously (64 lanes x 32 B = 2 KB)
// and scatters 16 B granule stores at 2 KB stride -- stores don't stall,
// and sibling waves fill neighboring r of the same line (write-combine).
// Output bytes and cvt2 pairing bit-identical to rounds 2-4.
__global__ __launch_bounds__(256) void cvt_bf16_kernel(const float* __restrict__ src,
                                                       unsigned* __restrict__ dst) {
    const int RB = blockIdx.x >> 3;          // 256 row-blocks
    const int r0 = (blockIdx.x & 7) * 16;    // 16-row group within block
    const int w    = threadIdx.x >> 6;       // wave 0..3
    const int lane = threadIdx.x & 63;       // = og
#pragma unroll
    for (int k = 0; k < 4; ++k) {
        const int r = r0 + k * 4 + w;        // covers r0..r0+15 exactly once
        const float* p = src + (size_t)(RB * 128 + r) * DDIM + lane * 8;
        const float4 a = *(const float4*)p;          // wave: 2 KB contiguous
        const float4 b = *(const float4*)(p + 4);
        uint4 v;
        v.x = cvt2(a.x, a.y); v.y = cvt2(a.z, a.w);
        v.z = cvt2(b.x, b.y); v.w = cvt2(b.z, b.w);
        *(uint4*)(dst + (size_t)RB * 32768 + lane * 512 + r * 4) = v;
    }
}

// fp32 codebook -> bf16 in fragment-major (octet-transposed) order:
// granule (g, k) of row k stored at ebT[(g*KC + k)*16B]. Coalesced writes;
// scattered reads absorbed by L2/L3 (one-time 8 MB transform).
__global__ __launch_bounds__(256) void cvt_ebT_kernel(const float* __restrict__ src,
                                                      unsigned* __restrict__ dst) {
    const int o = blockIdx.x * 256 + threadIdx.x;   // output granule index
    const int k = o & (KC - 1);
    const int g = o >> 13;                          // KC = 8192
    const float* p = src + (size_t)k * DDIM + g * 8;
    const float4 a = *(const float4*)p;
    const float4 b = *(const float4*)(p + 4);
    uint4 v;
    v.x = cvt2(a.x, a.y); v.y = cvt2(a.z, a.w);
    v.z = cvt2(b.x, b.y); v.w = cvt2(b.z, b.w);
    *(uint4*)(dst + (size_t)o * 4) = v;
}

// sum of squares, one row per 64-thread wave. Per-row arithmetic is
// BITWISE-IDENTICAL to all prior rounds -- DO NOT touch.
__global__ __launch_bounds__(256) void rownorm_kernel(const float* __restrict__ src,
                                                      float* __restrict__ dst) {
    const int row  = blockIdx.x * 4 + (threadIdx.x >> 6);
    const int lane = threadIdx.x & 63;
    const float* p = src + (size_t)row * DDIM;
    float s = 0.0f;
#pragma unroll
    for (int i = 0; i < DDIM / 64; ++i) {
        float v = p[lane + i * 64];
        s = __builtin_fmaf(v, v, s);
    }
#pragma unroll
    for (int off = 32; off > 0; off >>= 1) s += __shfl_down(s, off, 64);
    if (lane == 0) dst[row] = s;
}

__global__ __launch_bounds__(256) void semax_kernel(const float* __restrict__ sume,
                                                    float* __restrict__ semax) {
    __shared__ float red[256];
    float m = 0.f;
    for (int i = threadIdx.x; i < KC; i += 256) m = fmaxf(m, sume[i]);
    red[threadIdx.x] = m;
    __syncthreads();
    for (int s = 128; s > 0; s >>= 1) {
        if (threadIdx.x < s) red[threadIdx.x] = fmaxf(red[threadIdx.x], red[threadIdx.x + s]);
        __syncthreads();
    }
    if (threadIdx.x == 0) semax[0] = sqrtf(red[0]);
}

// bf16 MFMA approx-score GEMM + per-(row, code-tile) (min, argmin, 2ndmin).
// Round-13 = the verified round-2 structure EXACTLY (332.2 us measured):
//  * counted-vmcnt pipeline: raw s_barrier + s_waitcnt vmcnt(6) per iter
//    (never 0 in the loop); X rotates 3 LDS buffers, B rotates 3 reg sets.
//  * octet-major xb: X staging = verbatim linear 8 KB copy; A ds_reads are
//    256 B contiguous per 16-lane group -> conflicts ~3e6 (epilogue only).
//  * implicit nb%8 -> XCD pinning (bid = mb*64+nb): each XCD's B working
//    set is 1 MB (L2-resident); X fetched once per XCD. FETCH ~ 135 MB.
//    DO NOT remap blocks (round-3: 541 MB, -56 us).
//  * stats stored [nb][row]: 512 B contiguous stores (WRITE 24.6 MB);
//    measured 5 us faster than [row][tile], and free for rescore (round-2
//    vs round-4 rest identical).
__global__ __launch_bounds__(256) void gemm_filter_kernel(
        const unsigned* __restrict__ xb, const unsigned* __restrict__ ebT,
        const float* __restrict__ sume,
        float* __restrict__ lmin, float* __restrict__ l2nd, int* __restrict__ lidx) {
    __shared__ alignas(16) char smem[24576];   // X 3 x 8 KB; epilogue overlay

    const int tid  = threadIdx.x;
    const int nb   = blockIdx.x & (NTILE - 1);
    const int mb   = blockIdx.x >> 6;
    const int row0 = mb * 128, col0 = nb * 128;
    const int lane = tid & 63, w = tid >> 6;
    const int wy = w >> 1, wx = w & 1;
    const int l15 = lane & 15, q4 = lane >> 4;   // q4 in [0,4)

    f32x4 acc[4][4];
#pragma unroll
    for (int i = 0; i < 4; ++i)
#pragma unroll
        for (int j = 0; j < 4; ++j) acc[i][j] = f32x4{0.f, 0.f, 0.f, 0.f};

    // X staging: region R = w*2+t, 1 KB linear per gload_lds, source==dest
    // layout (verbatim copy of the 8 KB (mb, it) tile).
    const char* xg[2];
#pragma unroll
    for (int t = 0; t < 2; ++t)
        xg[t] = (const char*)xb + (size_t)mb * 131072 + ((w * 2 + t) << 10) + (lane << 4);
    // A-fragment byte offset in octet-major tile: o=q4, row=64*wy+16i+l15
    const int aoff = (q4 << 11) + ((64 * wy + l15) << 4);   // + i*256

    // B global base: granule (g = q4, col = col0 + 64wx + l15), u32 units
    const unsigned* bptr = ebT + ((size_t)(q4 * KC + col0 + 64 * wx + l15)) * 4;
    // j-stride: 16 cols = 64 u32; tile-stride: 4*KC granules = 131072 u32

    short8 B[3][4];

    // prologue: stage tiles 0,1 (X -> LDS bufs 0,1; B -> reg sets 0,1)
#pragma unroll
    for (int p = 0; p < 2; ++p) {
#pragma unroll
        for (int t = 0; t < 2; ++t)
            __builtin_amdgcn_global_load_lds((gchar_t*)(xg[t] + p * 8192),
                (lchar_t*)(smem + p * 8192 + ((w * 2 + t) << 10) + (lane << 4)), 16, 0, 0);
        const unsigned* bn = bptr + (size_t)p * 131072;
#pragma unroll
        for (int j = 0; j < 4; ++j) B[p][j] = *(const short8*)(bn + j * 64);
    }

#pragma unroll
    for (int it = 0; it < 16; ++it) {
        // Drain whole issue-group of tile `it` (6 VMEM: 2 X-DMA + 4 B),
        // keep tile it+1's group (6) in flight across the barrier.
        if (it < 15) asm volatile("s_waitcnt vmcnt(6)" ::: "memory");
        else         asm volatile("s_waitcnt vmcnt(0)" ::: "memory");
        __builtin_amdgcn_sched_barrier(0);
        __builtin_amdgcn_s_barrier();
        __builtin_amdgcn_sched_barrier(0);
        // issue tile it+2: X into buf (it+2)%3 (= buf (it-1)%3, released by
        // the barrier above), B into reg set (it+2)%3.
        if (it + 2 < 16) {
#pragma unroll
            for (int t = 0; t < 2; ++t)
                __builtin_amdgcn_global_load_lds((gchar_t*)(xg[t] + (it + 2) * 8192),
                    (lchar_t*)(smem + ((it + 2) % 3) * 8192 + ((w * 2 + t) << 10) + (lane << 4)), 16, 0, 0);
            const unsigned* bn = bptr + (size_t)(it + 2) * 131072;
#pragma unroll
            for (int j = 0; j < 4; ++j) B[(it + 2) % 3][j] = *(const short8*)(bn + j * 64);
        }
        __builtin_amdgcn_sched_barrier(0);
        // compute tile it
        const char* Xc = smem + (it % 3) * 8192;
        short8 A[4];
#pragma unroll
        for (int i = 0; i < 4; ++i)
            A[i] = *(const short8*)(Xc + aoff + i * 256);
#pragma unroll
        for (int i = 0; i < 4; ++i)
#pragma unroll
            for (int j = 0; j < 4; ++j)
                acc[i][j] = __builtin_amdgcn_mfma_f32_16x16x32_bf16(A[i], B[it % 3][j], acc[i][j], 0, 0, 0);
    }

    // ---- epilogue: per-row (min, argmin, 2ndmin) over this 128-code tile.
    float se[4];
#pragma unroll
    for (int j = 0; j < 4; ++j) se[j] = sume[col0 + 64 * wx + 16 * j + l15];

    __syncthreads();   // all waves done reading LDS before scratch overlays it
    float* pv1 = (float*)smem;             // [128][8]
    float* pv2 = (float*)(smem + 4096);    // [128][8]
    int*   pk1 = (int*)(smem + 8192);      // [128][8]

#pragma unroll
    for (int i = 0; i < 4; ++i) {
#pragma unroll
        for (int reg = 0; reg < 4; ++reg) {
            float v1 = FLT_MAX, v2 = FLT_MAX; int k1 = 0;
#pragma unroll
            for (int j = 0; j < 4; ++j) {
                const float s = __builtin_fmaf(-2.f, acc[i][j][reg], se[j]);
                const int c = col0 + 64 * wx + 16 * j + l15;
                if (s < v1) { v2 = v1; v1 = s; k1 = c; }
                else        { v2 = fminf(v2, s); }
            }
            // merge groups of 4 l15-lanes (exact ties leave l2nd==lmin -> the
            // rescore full-scans the tile, so tie-side argmin choice is moot)
#pragma unroll
            for (int m = 1; m <= 2; m <<= 1) {
                const float ov1 = __shfl_xor(v1, m, 64);
                const int   ok1 = __shfl_xor(k1, m, 64);
                const float ov2 = __shfl_xor(v2, m, 64);
                const float nv2 = fminf(fmaxf(v1, ov1), fminf(v2, ov2));
                if (ov1 < v1) { v1 = ov1; k1 = ok1; }
                v2 = nv2;
            }
            if ((l15 & 3) == 0) {
                const int rowl = 64 * wy + 16 * i + 4 * q4 + reg;
                const int c8   = wx * 4 + (l15 >> 2);
                const int slot = rowl * 8 + ((c8 + rowl) & 7);   // rotation swizzle
                pv1[slot] = v1; pv2[slot] = v2; pk1[slot] = k1;
            }
        }
    }
    __syncthreads();
    if (tid < 128) {
        float g1 = FLT_MAX, g2 = FLT_MAX; int gk = 0;
#pragma unroll
        for (int c = 0; c < 8; ++c) {
            const int slot = tid * 8 + ((c + tid) & 7);
            const float p1 = pv1[slot];
            const float p2 = pv2[slot];
            const int   pk = pk1[slot];
            if (p1 < g1) { g2 = fminf(g1, p2); g1 = p1; gk = pk; }
            else         { g2 = fminf(g2, p1); }
        }
        // transposed stat layout [nb][row]: 512 B contiguous per array
        const size_t o = (size_t)nb * NR + row0 + tid;
        lmin[o] = g1; l2nd[o] = g2; lidx[o] = gk;
    }
}

// exact rescore of provably-covering candidate set; one wave per row.
// margin = 2*(2^-7*||x||*||e||max + 6.5e-5): bf16-RNE dot error bound + two
// half-ulp(512) roundings in the exact formula, doubled for two-sidedness.
__global__ __launch_bounds__(256) void rescore_kernel(
        const float* __restrict__ x, const float* __restrict__ e,
        const float* __restrict__ sumx, const float* __restrict__ sume,
        const float* __restrict__ semax,
        const float* __restrict__ lmin, const float* __restrict__ l2nd,
        const int* __restrict__ lidx, int* __restrict__ inds) {
    __shared__ float xr[4][DDIM];
    __shared__ int list[4][64];

    const int w = threadIdx.x >> 6, lane = threadIdx.x & 63;
    const int row = blockIdx.x * 4 + w;

    // transposed stat layout [tile][row] (written coalesced by the gemm;
    // measured identical rescore cost to [row][tile] -- rounds 2 vs 4)
    const float lm = lmin[(size_t)lane * NR + row];
    const float l2 = l2nd[(size_t)lane * NR + row];
    const int   li = lidx[(size_t)lane * NR + row];

    float mr = lm;
#pragma unroll
    for (int m = 1; m < 64; m <<= 1) mr = fminf(mr, __shfl_xor(mr, m, 64));

    const float sx  = sumx[row];
    const float thr = mr + (0.0157f * sqrtf(sx) * semax[0] + 1.4e-4f);

    const bool single = (lm <= thr) && (l2 > thr);
    const unsigned long long bs = __ballot(single);
    const int pos = __popcll(bs & ((1ull << lane) - 1ull));
    if (single) list[w][pos] = li;
    const int nS = __popcll(bs);
    unsigned long long bf = __ballot(l2 <= thr);

    {
        const float* px = x + (size_t)row * DDIM + lane * 8;
        *(float4*)(&xr[w][lane * 8])     = *(const float4*)(px);
        *(float4*)(&xr[w][lane * 8 + 4]) = *(const float4*)(px + 4);
    }
    __syncthreads();

    float bd = FLT_MAX; int bk = 0x7fffffff;
    // exact dist: float4 loads, FMA order identical to all prior rounds
#define EVAL(KK)                                                             \
    {                                                                        \
        const int k_ = (KK);                                                 \
        const float4* ep4 = (const float4*)(e + ((size_t)k_ << 9));          \
        float dot = 0.f;                                                     \
        _Pragma("unroll 4")                                                  \
        for (int d4 = 0; d4 < 128; ++d4) {                                   \
            const float4 ev = ep4[d4];                                       \
            const float4 xv = *(const float4*)(&xr[w][d4 * 4]);              \
            dot = __builtin_fmaf(xv.x, ev.x, dot);                           \
            dot = __builtin_fmaf(xv.y, ev.y, dot);                           \
            dot = __builtin_fmaf(xv.z, ev.z, dot);                           \
            dot = __builtin_fmaf(xv.w, ev.w, dot);                           \
        }                                                                    \
        const float t1   = __fadd_rn(sx, sume[k_]);                          \
        const float dist = __fsub_rn(t1, __fadd_rn(dot, dot));               \
        if (dist < bd || (dist == bd && k_ < bk)) { bd = dist; bk = k_; }    \
    }

    if (lane < nS) EVAL(list[w][lane]);
    while (bf) {
        const int t = __ffsll((long long)bf) - 1;
        bf &= bf - 1;
        EVAL(128 * t + lane);
        EVAL(128 * t + 64 + lane);
    }
#undef EVAL

#pragma unroll
    for (int m = 1; m < 64; m <<= 1) {
        const float od = __shfl_xor(bd, m, 64);
        const int   ok = __shfl_xor(bk, m, 64);
        if (od < bd || (od == bd && ok < bk)) { bd = od; bk = ok; }
    }
    if (lane == 0) inds[row] = bk;
}

// out = x + (e[ind] - x), exact elementwise fp32 STE
__global__ __launch_bounds__(256) void writeout_kernel(const float* __restrict__ x,
                                                       const float* __restrict__ e,
                                                       const int* __restrict__ inds,
                                                       float* __restrict__ out) {
    const int t  = blockIdx.x * blockDim.x + threadIdx.x;
    const int n  = t >> 7;
    const int dq = (t & 127) * 4;
    const int ind = inds[n];
    const float4 xv = *(const float4*)(x + (size_t)n * DDIM + dq);
    const float4 ev = *(const float4*)(e + (size_t)ind * DDIM + dq);
    float4 o;
    o.x = __fadd_rn(xv.x, __fsub_rn(ev.x, xv.x));
    o.y = __fadd_rn(xv.y, __fsub_rn(ev.y, xv.y));
    o.z = __fadd_rn(xv.z, __fsub_rn(ev.z, xv.z));
    o.w = __fadd_rn(xv.w, __fsub_rn(ev.w, xv.w));
    *(float4*)(out + (size_t)n * DDIM + dq) = o;
}

extern "C" void kernel_launch(void* const* d_in, const int* in_sizes, int n_in,
                              void* d_out, int out_size, void* d_ws, size_t ws_size,
                              hipStream_t stream) {
    const float* lat = (const float*)d_in[0];   // (16,2048,512) fp32
    const float* emb = (const float*)d_in[1];   // (8192,512) fp32
    float* out = (float*)d_out;

    char* ws = (char*)d_ws;
    size_t off = 0;
    float*    sume  = (float*)(ws + off);    off += (size_t)KC * 4;
    float*    sumx  = (float*)(ws + off);    off += (size_t)NR * 4;
    float*    semax = (float*)(ws + off);    off += 256;
    float*    lmin  = (float*)(ws + off);    off += (size_t)NR * NTILE * 4;
    float*    l2nd  = (float*)(ws + off);    off += (size_t)NR * NTILE * 4;
    int*      lidx  = (int*)  (ws + off);    off += (size_t)NR * NTILE * 4;
    int*      inds  = (int*)  (ws + off);    off += (size_t)NR * 4;
    unsigned* xb    = (unsigned*)(ws + off); off += (size_t)NR * DDIM * 2;
    unsigned* ebT   = (unsigned*)(ws + off); off += (size_t)KC * DDIM * 2;

    cvt_bf16_kernel<<<2048, 256, 0, stream>>>(lat, xb);            // 256 RB x 8 row-groups
    cvt_ebT_kernel<<<(KC * DDIM / 8) / 256, 256, 0, stream>>>(emb, ebT);
    rownorm_kernel<<<KC / 4, 256, 0, stream>>>(emb, sume);
    rownorm_kernel<<<NR / 4, 256, 0, stream>>>(lat, sumx);
    semax_kernel<<<1, 256, 0, stream>>>(sume, semax);
    gemm_filter_kernel<<<(NR / 128) * NTILE, 256, 0, stream>>>(xb, ebT, sume, lmin, l2nd, lidx);
    rescore_kernel<<<NR / 4, 256, 0, stream>>>(lat, emb, sumx, sume, semax, lmin, l2nd, lidx, inds);
    writeout_kernel<<<(NR * DDIM / 4) / 256, 256, 0, stream>>>(lat, emb, inds, out);
}

// Round 6
// 716.789 us; speedup vs baseline: 1.1018x; 1.0133x over previous
//
#include <hip/hip_runtime.h>
#include <hip/hip_bf16.h>
#include <float.h>

#define NR    32768
#define DDIM  512
#define KC    8192
#define NTILE 64      // KC / 128 code-tiles

typedef __attribute__((ext_vector_type(8))) short short8;   // 8 bf16 = 4 VGPR
typedef __attribute__((ext_vector_type(4))) float f32x4;
typedef const __attribute__((address_space(1))) char gchar_t;
typedef __attribute__((address_space(3))) char lchar_t;

// pack two fp32 -> two bf16 (RNE) in one u32 (low word = first element)
__device__ inline unsigned cvt2(float a, float b) {
    __hip_bfloat162 h = __float22bfloat162_rn(float2{a, b});
    union { __hip_bfloat162 h; unsigned u; } v; v.h = h;
    return v.u;
}

// FUSED: fp32 latents -> (a) bf16 xb in octet-major GEMM-staging order and
// (b) sumx row sum-of-squares. One wave per row. The cvt body is verbatim
// round-5 (coalesced 2 KB/wave row read, 16 B granule store at 2 KB stride);
// the norm body is the BITWISE-IDENTICAL rownorm chain (scalar p[lane+i*64]
// loads -- L1/L2-hot after the vector read -- same FMA order, same shfl
// reduce). Saves one full 64 MB pass over lat + one launch vs split kernels.
__global__ __launch_bounds__(256) void lat_prep_kernel(const float* __restrict__ src,
                                                       unsigned* __restrict__ xb,
                                                       float* __restrict__ sumx) {
    const int w    = threadIdx.x >> 6;
    const int lane = threadIdx.x & 63;
    const int row  = blockIdx.x * 4 + w;
    const float* p = src + (size_t)row * DDIM;

    // ---- cvt (octet-major): granule og = lane of row `row`
    {
        const float4 a = *(const float4*)(p + lane * 8);     // wave: 2 KB contiguous
        const float4 b = *(const float4*)(p + lane * 8 + 4);
        uint4 v;
        v.x = cvt2(a.x, a.y); v.y = cvt2(a.z, a.w);
        v.z = cvt2(b.x, b.y); v.w = cvt2(b.z, b.w);
        const int RB = row >> 7, r = row & 127;
        *(uint4*)(xb + (size_t)RB * 32768 + lane * 512 + r * 4) = v;
    }

    // ---- rownorm: BITWISE-IDENTICAL to all prior rounds -- DO NOT touch.
    float s = 0.0f;
#pragma unroll
    for (int i = 0; i < DDIM / 64; ++i) {
        float v = p[lane + i * 64];
        s = __builtin_fmaf(v, v, s);
    }
#pragma unroll
    for (int off = 32; off > 0; off >>= 1) s += __shfl_down(s, off, 64);
    if (lane == 0) sumx[row] = s;
}

// FUSED: fp32 codebook -> (a) bf16 ebT in fragment-major (octet-transposed)
// order and (b) sume row sum-of-squares. One wave per codebook row k.
// cvt values identical to the old cvt_ebT (same cvt2 on same floats; granule
// (g=lane, k) at ebT[(lane*KC + k)*16B]); norm chain bitwise-identical.
__global__ __launch_bounds__(256) void emb_prep_kernel(const float* __restrict__ src,
                                                       unsigned* __restrict__ ebT,
                                                       float* __restrict__ sume) {
    const int w    = threadIdx.x >> 6;
    const int lane = threadIdx.x & 63;
    const int k    = blockIdx.x * 4 + w;
    const float* p = src + (size_t)k * DDIM;

    // ---- cvt: granule g = lane of row k -> scattered 16 B store (L2-combined)
    {
        const float4 a = *(const float4*)(p + lane * 8);     // wave: 2 KB contiguous
        const float4 b = *(const float4*)(p + lane * 8 + 4);
        uint4 v;
        v.x = cvt2(a.x, a.y); v.y = cvt2(a.z, a.w);
        v.z = cvt2(b.x, b.y); v.w = cvt2(b.z, b.w);
        *(uint4*)(ebT + ((size_t)lane * KC + k) * 4) = v;
    }

    // ---- rownorm: BITWISE-IDENTICAL to all prior rounds -- DO NOT touch.
    float s = 0.0f;
#pragma unroll
    for (int i = 0; i < DDIM / 64; ++i) {
        float v = p[lane + i * 64];
        s = __builtin_fmaf(v, v, s);
    }
#pragma unroll
    for (int off = 32; off > 0; off >>= 1) s += __shfl_down(s, off, 64);
    if (lane == 0) sume[k] = s;
}

__global__ __launch_bounds__(256) void semax_kernel(const float* __restrict__ sume,
                                                    float* __restrict__ semax) {
    __shared__ float red[256];
    float m = 0.f;
    for (int i = threadIdx.x; i < KC; i += 256) m = fmaxf(m, sume[i]);
    red[threadIdx.x] = m;
    __syncthreads();
    for (int s = 128; s > 0; s >>= 1) {
        if (threadIdx.x < s) red[threadIdx.x] = fmaxf(red[threadIdx.x], red[threadIdx.x + s]);
        __syncthreads();
    }
    if (threadIdx.x == 0) semax[0] = sqrtf(red[0]);
}

// bf16 MFMA approx-score GEMM + per-(row, code-tile) (min, argmin, 2ndmin).
// The verified round-2/5 structure EXACTLY (329.2 us measured):
//  * counted-vmcnt pipeline: raw s_barrier + s_waitcnt vmcnt(6) per iter
//    (never 0 in the loop); X rotates 3 LDS buffers, B rotates 3 reg sets.
//  * octet-major xb: X staging = verbatim linear 8 KB copy; A ds_reads are
//    256 B contiguous per 16-lane group -> conflicts ~3e6 (epilogue only).
//  * implicit nb%8 -> XCD pinning (bid = mb*64+nb): each XCD's B working
//    set is 1 MB (L2-resident); X fetched once per XCD. FETCH ~ 135 MB.
//    DO NOT remap blocks (round-3: 541 MB, -56 us).
//  * stats stored [nb][row]: 512 B contiguous stores (WRITE 24.6 MB).
__global__ __launch_bounds__(256) void gemm_filter_kernel(
        const unsigned* __restrict__ xb, const unsigned* __restrict__ ebT,
        const float* __restrict__ sume,
        float* __restrict__ lmin, float* __restrict__ l2nd, int* __restrict__ lidx) {
    __shared__ alignas(16) char smem[24576];   // X 3 x 8 KB; epilogue overlay

    const int tid  = threadIdx.x;
    const int nb   = blockIdx.x & (NTILE - 1);
    const int mb   = blockIdx.x >> 6;
    const int row0 = mb * 128, col0 = nb * 128;
    const int lane = tid & 63, w = tid >> 6;
    const int wy = w >> 1, wx = w & 1;
    const int l15 = lane & 15, q4 = lane >> 4;   // q4 in [0,4)

    f32x4 acc[4][4];
#pragma unroll
    for (int i = 0; i < 4; ++i)
#pragma unroll
        for (int j = 0; j < 4; ++j) acc[i][j] = f32x4{0.f, 0.f, 0.f, 0.f};

    // X staging: region R = w*2+t, 1 KB linear per gload_lds, source==dest
    // layout (verbatim copy of the 8 KB (mb, it) tile).
    const char* xg[2];
#pragma unroll
    for (int t = 0; t < 2; ++t)
        xg[t] = (const char*)xb + (size_t)mb * 131072 + ((w * 2 + t) << 10) + (lane << 4);
    // A-fragment byte offset in octet-major tile: o=q4, row=64*wy+16i+l15
    const int aoff = (q4 << 11) + ((64 * wy + l15) << 4);   // + i*256

    // B global base: granule (g = q4, col = col0 + 64wx + l15), u32 units
    const unsigned* bptr = ebT + ((size_t)(q4 * KC + col0 + 64 * wx + l15)) * 4;
    // j-stride: 16 cols = 64 u32; tile-stride: 4*KC granules = 131072 u32

    short8 B[3][4];

    // prologue: stage tiles 0,1 (X -> LDS bufs 0,1; B -> reg sets 0,1)
#pragma unroll
    for (int p = 0; p < 2; ++p) {
#pragma unroll
        for (int t = 0; t < 2; ++t)
            __builtin_amdgcn_global_load_lds((gchar_t*)(xg[t] + p * 8192),
                (lchar_t*)(smem + p * 8192 + ((w * 2 + t) << 10) + (lane << 4)), 16, 0, 0);
        const unsigned* bn = bptr + (size_t)p * 131072;
#pragma unroll
        for (int j = 0; j < 4; ++j) B[p][j] = *(const short8*)(bn + j * 64);
    }

#pragma unroll
    for (int it = 0; it < 16; ++it) {
        // Drain whole issue-group of tile `it` (6 VMEM: 2 X-DMA + 4 B),
        // keep tile it+1's group (6) in flight across the barrier.
        if (it < 15) asm volatile("s_waitcnt vmcnt(6)" ::: "memory");
        else         asm volatile("s_waitcnt vmcnt(0)" ::: "memory");
        __builtin_amdgcn_sched_barrier(0);
        __builtin_amdgcn_s_barrier();
        __builtin_amdgcn_sched_barrier(0);
        // issue tile it+2: X into buf (it+2)%3 (= buf (it-1)%3, released by
        // the barrier above), B into reg set (it+2)%3.
        if (it + 2 < 16) {
#pragma unroll
            for (int t = 0; t < 2; ++t)
                __builtin_amdgcn_global_load_lds((gchar_t*)(xg[t] + (it + 2) * 8192),
                    (lchar_t*)(smem + ((it + 2) % 3) * 8192 + ((w * 2 + t) << 10) + (lane << 4)), 16, 0, 0);
            const unsigned* bn = bptr + (size_t)(it + 2) * 131072;
#pragma unroll
            for (int j = 0; j < 4; ++j) B[(it + 2) % 3][j] = *(const short8*)(bn + j * 64);
        }
        __builtin_amdgcn_sched_barrier(0);
        // compute tile it
        const char* Xc = smem + (it % 3) * 8192;
        short8 A[4];
#pragma unroll
        for (int i = 0; i < 4; ++i)
            A[i] = *(const short8*)(Xc + aoff + i * 256);
#pragma unroll
        for (int i = 0; i < 4; ++i)
#pragma unroll
            for (int j = 0; j < 4; ++j)
                acc[i][j] = __builtin_amdgcn_mfma_f32_16x16x32_bf16(A[i], B[it % 3][j], acc[i][j], 0, 0, 0);
    }

    // ---- epilogue: per-row (min, argmin, 2ndmin) over this 128-code tile.
    float se[4];
#pragma unroll
    for (int j = 0; j < 4; ++j) se[j] = sume[col0 + 64 * wx + 16 * j + l15];

    __syncthreads();   // all waves done reading LDS before scratch overlays it
    float* pv1 = (float*)smem;             // [128][8]
    float* pv2 = (float*)(smem + 4096);    // [128][8]
    int*   pk1 = (int*)(smem + 8192);      // [128][8]

#pragma unroll
    for (int i = 0; i < 4; ++i) {
#pragma unroll
        for (int reg = 0; reg < 4; ++reg) {
            float v1 = FLT_MAX, v2 = FLT_MAX; int k1 = 0;
#pragma unroll
            for (int j = 0; j < 4; ++j) {
                const float s = __builtin_fmaf(-2.f, acc[i][j][reg], se[j]);
                const int c = col0 + 64 * wx + 16 * j + l15;
                if (s < v1) { v2 = v1; v1 = s; k1 = c; }
                else        { v2 = fminf(v2, s); }
            }
            // merge groups of 4 l15-lanes (exact ties leave l2nd==lmin -> the
            // rescore full-scans the tile, so tie-side argmin choice is moot)
#pragma unroll
            for (int m = 1; m <= 2; m <<= 1) {
                const float ov1 = __shfl_xor(v1, m, 64);
                const int   ok1 = __shfl_xor(k1, m, 64);
                const float ov2 = __shfl_xor(v2, m, 64);
                const float nv2 = fminf(fmaxf(v1, ov1), fminf(v2, ov2));
                if (ov1 < v1) { v1 = ov1; k1 = ok1; }
                v2 = nv2;
            }
            if ((l15 & 3) == 0) {
                const int rowl = 64 * wy + 16 * i + 4 * q4 + reg;
                const int c8   = wx * 4 + (l15 >> 2);
                const int slot = rowl * 8 + ((c8 + rowl) & 7);   // rotation swizzle
                pv1[slot] = v1; pv2[slot] = v2; pk1[slot] = k1;
            }
        }
    }
    __syncthreads();
    if (tid < 128) {
        float g1 = FLT_MAX, g2 = FLT_MAX; int gk = 0;
#pragma unroll
        for (int c = 0; c < 8; ++c) {
            const int slot = tid * 8 + ((c + tid) & 7);
            const float p1 = pv1[slot];
            const float p2 = pv2[slot];
            const int   pk = pk1[slot];
            if (p1 < g1) { g2 = fminf(g1, p2); g1 = p1; gk = pk; }
            else         { g2 = fminf(g2, p1); }
        }
        // transposed stat layout [nb][row]: 512 B contiguous per array
        const size_t o = (size_t)nb * NR + row0 + tid;
        lmin[o] = g1; l2nd[o] = g2; lidx[o] = gk;
    }
}

// exact rescore of provably-covering candidate set; one wave per row.
// margin = 2*(2^-7*||x||*||e||max + 6.5e-5): bf16-RNE dot error bound + two
// half-ulp(512) roundings in the exact formula, doubled for two-sidedness.
__global__ __launch_bounds__(256) void rescore_kernel(
        const float* __restrict__ x, const float* __restrict__ e,
        const float* __restrict__ sumx, const float* __restrict__ sume,
        const float* __restrict__ semax,
        const float* __restrict__ lmin, const float* __restrict__ l2nd,
        const int* __restrict__ lidx, int* __restrict__ inds) {
    __shared__ float xr[4][DDIM];
    __shared__ int list[4][64];

    const int w = threadIdx.x >> 6, lane = threadIdx.x & 63;
    const int row = blockIdx.x * 4 + w;

    // transposed stat layout [tile][row] (written coalesced by the gemm;
    // measured identical rescore cost to [row][tile] -- rounds 2 vs 4)
    const float lm = lmin[(size_t)lane * NR + row];
    const float l2 = l2nd[(size_t)lane * NR + row];
    const int   li = lidx[(size_t)lane * NR + row];

    float mr = lm;
#pragma unroll
    for (int m = 1; m < 64; m <<= 1) mr = fminf(mr, __shfl_xor(mr, m, 64));

    const float sx  = sumx[row];
    const float thr = mr + (0.0157f * sqrtf(sx) * semax[0] + 1.4e-4f);

    const bool single = (lm <= thr) && (l2 > thr);
    const unsigned long long bs = __ballot(single);
    const int pos = __popcll(bs & ((1ull << lane) - 1ull));
    if (single) list[w][pos] = li;
    const int nS = __popcll(bs);
    unsigned long long bf = __ballot(l2 <= thr);

    {
        const float* px = x + (size_t)row * DDIM + lane * 8;
        *(float4*)(&xr[w][lane * 8])     = *(const float4*)(px);
        *(float4*)(&xr[w][lane * 8 + 4]) = *(const float4*)(px + 4);
    }
    __syncthreads();

    float bd = FLT_MAX; int bk = 0x7fffffff;
    // exact dist: float4 loads, FMA order identical to all prior rounds
#define EVAL(KK)                                                             \
    {                                                                        \
        const int k_ = (KK);                                                 \
        const float4* ep4 = (const float4*)(e + ((size_t)k_ << 9));          \
        float dot = 0.f;                                                     \
        _Pragma("unroll 4")                                                  \
        for (int d4 = 0; d4 < 128; ++d4) {                                   \
            const float4 ev = ep4[d4];                                       \
            const float4 xv = *(const float4*)(&xr[w][d4 * 4]);              \
            dot = __builtin_fmaf(xv.x, ev.x, dot);                           \
            dot = __builtin_fmaf(xv.y, ev.y, dot);                           \
            dot = __builtin_fmaf(xv.z, ev.z, dot);                           \
            dot = __builtin_fmaf(xv.w, ev.w, dot);                           \
        }                                                                    \
        const float t1   = __fadd_rn(sx, sume[k_]);                          \
        const float dist = __fsub_rn(t1, __fadd_rn(dot, dot));               \
        if (dist < bd || (dist == bd && k_ < bk)) { bd = dist; bk = k_; }    \
    }

    if (lane < nS) EVAL(list[w][lane]);
    while (bf) {
        const int t = __ffsll((long long)bf) - 1;
        bf &= bf - 1;
        EVAL(128 * t + lane);
        EVAL(128 * t + 64 + lane);
    }
#undef EVAL

#pragma unroll
    for (int m = 1; m < 64; m <<= 1) {
        const float od = __shfl_xor(bd, m, 64);
        const int   ok = __shfl_xor(bk, m, 64);
        if (od < bd || (od == bd && ok < bk)) { bd = od; bk = ok; }
    }
    if (lane == 0) inds[row] = bk;
}

// out = x + (e[ind] - x), exact elementwise fp32 STE
__global__ __launch_bounds__(256) void writeout_kernel(const float* __restrict__ x,
                                                       const float* __restrict__ e,
                                                       const int* __restrict__ inds,
                                                       float* __restrict__ out) {
    const int t  = blockIdx.x * blockDim.x + threadIdx.x;
    const int n  = t >> 7;
    const int dq = (t & 127) * 4;
    const int ind = inds[n];
    const float4 xv = *(const float4*)(x + (size_t)n * DDIM + dq);
    const float4 ev = *(const float4*)(e + (size_t)ind * DDIM + dq);
    float4 o;
    o.x = __fadd_rn(xv.x, __fsub_rn(ev.x, xv.x));
    o.y = __fadd_rn(xv.y, __fsub_rn(ev.y, xv.y));
    o.z = __fadd_rn(xv.z, __fsub_rn(ev.z, xv.z));
    o.w = __fadd_rn(xv.w, __fsub_rn(ev.w, xv.w));
    *(float4*)(out + (size_t)n * DDIM + dq) = o;
}

extern "C" void kernel_launch(void* const* d_in, const int* in_sizes, int n_in,
                              void* d_out, int out_size, void* d_ws, size_t ws_size,
                              hipStream_t stream) {
    const float* lat = (const float*)d_in[0];   // (16,2048,512) fp32
    const float* emb = (const float*)d_in[1];   // (8192,512) fp32
    float* out = (float*)d_out;

    char* ws = (char*)d_ws;
    size_t off = 0;
    float*    sume  = (float*)(ws + off);    off += (size_t)KC * 4;
    float*    sumx  = (float*)(ws + off);    off += (size_t)NR * 4;
    float*    semax = (float*)(ws + off);    off += 256;
    float*    lmin  = (float*)(ws + off);    off += (size_t)NR * NTILE * 4;
    float*    l2nd  = (float*)(ws + off);    off += (size_t)NR * NTILE * 4;
    int*      lidx  = (int*)  (ws + off);    off += (size_t)NR * NTILE * 4;
    int*      inds  = (int*)  (ws + off);    off += (size_t)NR * 4;
    unsigned* xb    = (unsigned*)(ws + off); off += (size_t)NR * DDIM * 2;
    unsigned* ebT   = (unsigned*)(ws + off); off += (size_t)KC * DDIM * 2;

    lat_prep_kernel<<<NR / 4, 256, 0, stream>>>(lat, xb, sumx);
    emb_prep_kernel<<<KC / 4, 256, 0, stream>>>(emb, ebT, sume);
    semax_kernel<<<1, 256, 0, stream>>>(sume, semax);
    gemm_filter_kernel<<<(NR / 128) * NTILE, 256, 0, stream>>>(xb, ebT, sume, lmin, l2nd, lidx);
    rescore_kernel<<<NR / 4, 256, 0, stream>>>(lat, emb, sumx, sume, semax, lmin, l2nd, lidx, inds);
    writeout_kernel<<<(NR * DDIM / 4) / 256, 256, 0, stream>>>(lat, emb, inds, out);
}